// Round 15
// baseline (141.027 us; speedup 1.0000x reference)
//
#include <hip/hip_runtime.h>
#include <hip/hip_bf16.h>

// Problem dims (fixed)
#define T_DIM 256
#define B_DIM 256
#define F_DIM 128
#define H1_DIM 256
#define H_DIM 128
#define Q_DIM 4
#define TAGS 32
#define TB (T_DIM * B_DIM)   // 65536 rows

typedef __attribute__((ext_vector_type(8))) short bf16x8;
typedef __attribute__((ext_vector_type(4))) float f32x4;
typedef __attribute__((ext_vector_type(2))) float f32x2;

__device__ __forceinline__ float rcpf(float x) { return __builtin_amdgcn_rcpf(x); }
__device__ __forceinline__ float exp2f_hw(float x) { return __builtin_amdgcn_exp2f(x); }

__device__ __forceinline__ float tanhf_fast(float x) {
    float e = exp2f_hw(2.885390081777927f * x);   // exp(2x)
    return 1.0f - 2.0f * rcpf(e + 1.0f);
}
__device__ __forceinline__ float sigf(float x) {
    return rcpf(1.0f + exp2f_hw(-1.4426950408889634f * x));
}

__device__ __forceinline__ unsigned short f2bf(float f) {
    __hip_bfloat16 h = __float2bfloat16(f);   // RNE
    return *reinterpret_cast<unsigned short*>(&h);
}

// Packed f32 ops (VOP3P): 2 f32 lanes per instruction.
__device__ __forceinline__ f32x2 pk_mul2(f32x2 a, f32x2 b) {
    f32x2 d;
    asm("v_pk_mul_f32 %0, %1, %2" : "=v"(d) : "v"(a), "v"(b));
    return d;
}
__device__ __forceinline__ f32x2 pk_add2(f32x2 a, f32x2 b) {
    f32x2 d;
    asm("v_pk_add_f32 %0, %1, %2" : "=v"(d) : "v"(a), "v"(b));
    return d;
}
__device__ __forceinline__ f32x2 pk_fma2(f32x2 a, f32x2 b, f32x2 c) {
    f32x2 d;
    asm("v_pk_fma_f32 %0, %1, %2, %3" : "=v"(d) : "v"(a), "v"(b), "v"(c));
    return d;
}

// DPP cross-lane add within quad: CTRL=0xB1 -> lane^1, CTRL=0x4E -> lane^2
template<int CTRL>
__device__ __forceinline__ float dpp_xadd(float x) {
    int t = __builtin_amdgcn_update_dpp(0, __float_as_int(x), CTRL, 0xF, 0xF, true);
    return x + __int_as_float(t);
}

// ---------------------------------------------------------------------------
// Kernel 0: weight prep (blocks 0..63) + adj transpose (blocks 64..127).
// ---------------------------------------------------------------------------
__global__ __launch_bounds__(256) void prep_transpose_kernel(
    const float* __restrict__ W1, const float* __restrict__ W2,
    const float* __restrict__ Win, const float* __restrict__ Wtag,
    const float* __restrict__ adj,
    unsigned short* __restrict__ W1p, unsigned short* __restrict__ W2p,
    unsigned short* __restrict__ Winxp, unsigned short* __restrict__ Wtagp,
    float* __restrict__ adjT)
{
    __shared__ float tile[32][33];
    const int tid = threadIdx.x;
    if (blockIdx.x >= 64) {
        const int blk = blockIdx.x - 64;
        const int bx = blk & 7, by = blk >> 3;
        const int lx = tid & 31, ly = (tid >> 5) * 4;
#pragma unroll
        for (int r = 0; r < 4; r++)
            tile[ly + r][lx] = adj[(long)(by * 32 + ly + r) * 256 + bx * 32 + lx];
        __syncthreads();
#pragma unroll
        for (int r = 0; r < 4; r++)
            adjT[(long)(bx * 32 + ly + r) * 256 + by * 32 + lx] = tile[lx][ly + r];
        return;
    }
    const int gid0 = blockIdx.x * 256 + tid;
    const int gstride = 64 * 256;
    for (int idx = gid0; idx < 32768; idx += gstride) {
        int e = idx & 7, l = (idx >> 3) & 63, t2 = idx >> 9;
        int nb = t2 & 15, kk = t2 >> 4;
        int k = kk * 32 + (l >> 4) * 8 + e, n = nb * 16 + (l & 15);
        W1p[idx] = f2bf(W1[k * 256 + n]);
    }
    for (int idx = gid0; idx < 32768; idx += gstride) {
        int e = idx & 7, l = (idx >> 3) & 63, t2 = idx >> 9;
        int nb = t2 & 7, kk = t2 >> 3;
        int k = kk * 32 + (l >> 4) * 8 + e, n = nb * 16 + (l & 15);
        W2p[idx] = f2bf(W2[k * 128 + n]);
    }
    for (int idx = gid0; idx < 2048; idx += gstride) {
        int e = idx & 7, l = (idx >> 3) & 63, kk = idx >> 9;
        int k = kk * 32 + (l >> 4) * 8 + e, o = l & 15;
        Winxp[idx] = f2bf(Win[(o >> 2) * 1024 + k * 4 + (o & 3)]);
    }
    for (int idx = gid0; idx < 4096; idx += gstride) {
        int e = idx & 7, l = (idx >> 3) & 63, t2 = idx >> 9;
        int nt = t2 & 1, kk = t2 >> 1;
        int k = kk * 32 + (l >> 4) * 8 + e, n = nt * 16 + (l & 15);
        Wtagp[idx] = f2bf(Wtag[k * 32 + n]);
    }
}

// ---------------------------------------------------------------------------
// Kernel 1: MFMA MLP + fused Win_x projection.  (unchanged)
// ---------------------------------------------------------------------------
__global__ __launch_bounds__(256) void mlp_mfma_kernel(
    const float* __restrict__ X, const unsigned short* __restrict__ W1p,
    const float* __restrict__ b1, const unsigned short* __restrict__ W2p,
    const float* __restrict__ b2, const unsigned short* __restrict__ Winxp,
    float* __restrict__ NSP)
{
    __shared__ __align__(16) unsigned short a1_s[64 * 256];
    __shared__ __align__(16) unsigned short xns_s[64 * 128];

    const int tid = threadIdx.x;
    const int w = tid >> 6;
    const int lane = tid & 63;
    const int lr = lane & 15;
    const int lg = lane >> 4;
    const long rowbase = (long)blockIdx.x * 64;

    char* const a1c = (char*)a1_s;
    char* const xnc = (char*)xns_s;

    {
        const int r = tid >> 2;
        const int qc = tid & 3;
        const float4* xg = (const float4*)(X + (rowbase + r) * 128 + qc * 32);
#pragma unroll
        for (int i = 0; i < 4; i++) {
            float4 lo = xg[i * 2], hi = xg[i * 2 + 1];
            bf16x8 v;
            v[0] = (short)f2bf(lo.x); v[1] = (short)f2bf(lo.y);
            v[2] = (short)f2bf(lo.z); v[3] = (short)f2bf(lo.w);
            v[4] = (short)f2bf(hi.x); v[5] = (short)f2bf(hi.y);
            v[6] = (short)f2bf(hi.z); v[7] = (short)f2bf(hi.w);
            int byte = (r * 256 + qc * 64 + i * 16) ^ ((r & 7) << 4);
            *(bf16x8*)(xnc + byte) = v;
        }
    }
    __syncthreads();

    {
        f32x4 acc[4][4];
#pragma unroll
        for (int mi = 0; mi < 4; mi++)
#pragma unroll
            for (int j = 0; j < 4; j++) acc[mi][j] = (f32x4){0.f, 0.f, 0.f, 0.f};

        const bf16x8* w1v = (const bf16x8*)W1p;
#pragma unroll
        for (int kk = 0; kk < 4; kk++) {
            bf16x8 af[4];
#pragma unroll
            for (int mi = 0; mi < 4; mi++) {
                int row = mi * 16 + lr;
                int byte = (row * 256 + kk * 64 + lg * 16) ^ ((row & 7) << 4);
                af[mi] = *(const bf16x8*)(xnc + byte);
            }
            bf16x8 bfv[4];
#pragma unroll
            for (int j = 0; j < 4; j++)
                bfv[j] = w1v[(kk * 16 + (w * 4 + j)) * 64 + lane];
#pragma unroll
            for (int mi = 0; mi < 4; mi++)
#pragma unroll
                for (int j = 0; j < 4; j++)
                    acc[mi][j] = __builtin_amdgcn_mfma_f32_16x16x32_bf16(
                        af[mi], bfv[j], acc[mi][j], 0, 0, 0);
        }

        float b1v[4];
#pragma unroll
        for (int j = 0; j < 4; j++) b1v[j] = b1[(w * 4 + j) * 16 + lr];
#pragma unroll
        for (int mi = 0; mi < 4; mi++)
#pragma unroll
            for (int j = 0; j < 4; j++)
#pragma unroll
                for (int reg = 0; reg < 4; reg++) {
                    int row = mi * 16 + lg * 4 + reg;
                    int col = (w * 4 + j) * 16 + lr;
                    float v = tanhf_fast(acc[mi][j][reg] + b1v[j]);
                    int byte = (row * 512 + col * 2) ^ ((row & 7) << 4);
                    *(unsigned short*)(a1c + byte) = f2bf(v);
                }
    }
    __syncthreads();

    {
        f32x4 acc[4][2];
#pragma unroll
        for (int mi = 0; mi < 4; mi++)
#pragma unroll
            for (int j = 0; j < 2; j++) acc[mi][j] = (f32x4){0.f, 0.f, 0.f, 0.f};

        const bf16x8* w2v = (const bf16x8*)W2p;
#pragma unroll
        for (int kk = 0; kk < 8; kk++) {
            bf16x8 af[4];
#pragma unroll
            for (int mi = 0; mi < 4; mi++) {
                int row = mi * 16 + lr;
                int byte = (row * 512 + kk * 64 + lg * 16) ^ ((row & 7) << 4);
                af[mi] = *(const bf16x8*)(a1c + byte);
            }
            bf16x8 bfv[2];
#pragma unroll
            for (int j = 0; j < 2; j++)
                bfv[j] = w2v[(kk * 8 + (w * 2 + j)) * 64 + lane];
#pragma unroll
            for (int mi = 0; mi < 4; mi++)
#pragma unroll
                for (int j = 0; j < 2; j++)
                    acc[mi][j] = __builtin_amdgcn_mfma_f32_16x16x32_bf16(
                        af[mi], bfv[j], acc[mi][j], 0, 0, 0);
        }

        float b2v[2];
#pragma unroll
        for (int j = 0; j < 2; j++) b2v[j] = b2[(w * 2 + j) * 16 + lr];
#pragma unroll
        for (int mi = 0; mi < 4; mi++)
#pragma unroll
            for (int j = 0; j < 2; j++)
#pragma unroll
                for (int reg = 0; reg < 4; reg++) {
                    int row = mi * 16 + lg * 4 + reg;
                    int col = (w * 2 + j) * 16 + lr;
                    float v = tanhf_fast(acc[mi][j][reg] + b2v[j]);
                    int byte = (row * 256 + col * 2) ^ ((row & 7) << 4);
                    *(unsigned short*)(xnc + byte) = f2bf(v);
                }
    }
    __syncthreads();

    {
        f32x4 acc = (f32x4){0.f, 0.f, 0.f, 0.f};
        const bf16x8* wxv = (const bf16x8*)Winxp;
#pragma unroll
        for (int kk = 0; kk < 4; kk++) {
            int row = w * 16 + lr;
            int byte = (row * 256 + kk * 64 + lg * 16) ^ ((row & 7) << 4);
            bf16x8 af = *(const bf16x8*)(xnc + byte);
            bf16x8 bfv = wxv[kk * 64 + lane];
            acc = __builtin_amdgcn_mfma_f32_16x16x32_bf16(af, bfv, acc, 0, 0, 0);
        }
#pragma unroll
        for (int reg = 0; reg < 4; reg++) {
            int row = w * 16 + lg * 4 + reg;
            NSP[(rowbase + row) * 16 + lr] = acc[reg];
        }
    }
}

// ---------------------------------------------------------------------------
// Kernel 3: AX[t,i,o] = b_in[o] + sum_j adj[i,j] * NSP[t,j,o]
// ---------------------------------------------------------------------------
__global__ __launch_bounds__(256) void aggx_kernel(
    const float* __restrict__ adjT, const float* __restrict__ NSP,
    const float* __restrict__ b_in, float* __restrict__ AX)
{
    __shared__ float4 nsp_s[256 * 4];
    const int tid = threadIdx.x;
    const int t = blockIdx.x;
    {
        const float4* g = (const float4*)(NSP + (long)t * 4096);
#pragma unroll
        for (int i = 0; i < 4; i++) nsp_s[tid + i * 256] = g[tid + i * 256];
    }
    __syncthreads();

    float4 acc[4];
#pragma unroll
    for (int p = 0; p < 4; p++) acc[p] = ((const float4*)b_in)[p];

    const float* arow = adjT + tid;
    float a[8], an[8];
#pragma unroll
    for (int m = 0; m < 8; m++) an[m] = arow[m * 256];
    for (int j0 = 0; j0 < 256; j0 += 8) {
#pragma unroll
        for (int m = 0; m < 8; m++) a[m] = an[m];
        if (j0 + 8 < 256) {
#pragma unroll
            for (int m = 0; m < 8; m++) an[m] = arow[(j0 + 8 + m) * 256];
        }
#pragma unroll
        for (int m = 0; m < 8; m++) {
            float av = a[m];
#pragma unroll
            for (int p = 0; p < 4; p++) {
                float4 nv = nsp_s[(j0 + m) * 4 + p];
                acc[p].x += av * nv.x; acc[p].y += av * nv.y;
                acc[p].z += av * nv.z; acc[p].w += av * nv.w;
            }
        }
    }
    float4* out = (float4*)(AX + (long)t * 4096 + tid * 16);
#pragma unroll
    for (int p = 0; p < 4; p++) out[p] = acc[p];
}

// ---------------------------------------------------------------------------
// Kernel 4: LSTM scan + FUSED tag head. TWO waves per batch element.
// Round-15: PARTIAL-Z EXCHANGE. Each wave dots only its OWN h-half (kept
// through an in-wave LDS round-trip) and exchanges a single scalar partial
// through a parity-double-buffered 1KB LDS slot. Post-barrier chain drops
// from {8 ds_read_b64 + 8 pk_fma + tree} to {1 ds_read_b32 + 1 add}.
// No cross-wave h traffic at all; h history still recorded for the head.
// ---------------------------------------------------------------------------
__device__ __forceinline__ int hhoff(int row, int inrow) {
    return (row * 512 + inrow) ^ ((row & 7) << 4);
}

__global__ __attribute__((amdgpu_waves_per_eu(1, 1))) __launch_bounds__(128)
void lstm_head_kernel(
    const float* __restrict__ AX, const float* __restrict__ Win,
    const float* __restrict__ Wout, const float* __restrict__ b_out,
    const unsigned short* __restrict__ Wtagp, const float* __restrict__ btag,
    float* __restrict__ OUT)
{
    __shared__ __align__(16) float hh[T_DIM * 128];   // 128 KB, swizzled rows
    __shared__ __align__(16) float zbuf[2 * 128];     // partial-z exchange (dbuf)
    char* const hhc = (char*)hh;

    const int tid = threadIdx.x;
    const int w = tid >> 6;        // wave: h-half owner (features w*64..w*64+63)
    const int lane = tid & 63;
    const int b = blockIdx.x;
    const int o = lane >> 2;
    const int s = lane & 3;
    const int g_o = o >> 2, q_o = o & 3;

    // own-half dot weights: wh2[m*2+p] = Win_h[w*64 + m*16+s*4+p*2 ..+1][o]
    f32x2 wh2[8];
#pragma unroll
    for (int m = 0; m < 4; m++)
#pragma unroll
        for (int p = 0; p < 2; p++) {
            int k0 = w * 64 + m * 16 + s * 4 + p * 2;
            f32x2 v;
            v.x = Win[g_o * 1024 + 512 + k0 * 4 + q_o];
            v.y = Win[g_o * 1024 + 512 + (k0 + 1) * 4 + q_o];
            wh2[m * 2 + p] = v;
        }

    // gate weights for THIS wave's feature f = w*64 + lane
    const int f = w * 64 + lane;
    float wo[4][4];
    float bo[4];
#pragma unroll
    for (int g = 0; g < 4; g++) {
        bo[g] = b_out[g * 128 + f];
#pragma unroll
        for (int q = 0; q < 4; q++)
            wo[g][q] = Wout[(g * 4 + q) * 128 + f];
    }

    const int own_off = w << 8;          // byte base of own half within a row
    const float axmask = (w == 0) ? 1.0f : 0.0f;   // only wave 0 adds ax
    const int zw_idx = (w << 6) + lane;            // write slot
    const int zr_idx = ((w ^ 1) << 6) + lane;      // partner slot
    int woffs[8], roffs[8];
#pragma unroll
    for (int sl = 0; sl < 8; sl++) {
        woffs[sl] = ((lane * 4) ^ (sl << 4)) + own_off;
        roffs[sl] = ((s * 16) ^ ((sl << 4) & 0x30)) + own_off;
    }

    float c = 0.f;
    f32x2 hz[8];   // own-half h pairs for the dot (zero = h(-1))
#pragma unroll
    for (int m = 0; m < 8; m++) hz[m] = (f32x2){0.f, 0.f};

    const float* axp = AX + (long)b * 16 + o;
    float ax_cur = axp[0];
    float ax_nxt = axp[B_DIM * 16];
    axp += 2 * B_DIM * 16;

    int vbase = 0;
    for (int tb = 0; tb < T_DIM; tb += 8) {
#pragma unroll
        for (int sl = 0; sl < 8; sl++) {
            const int sw6 = (sl << 4) & 0x40;
            // ---- own-half packed dot (8 pk_fma) ----
            f32x2 aA = pk_mul2(hz[0], wh2[0]);
            f32x2 aB = pk_mul2(hz[1], wh2[1]);
            aA = pk_fma2(hz[2], wh2[2], aA);
            aB = pk_fma2(hz[3], wh2[3], aB);
            aA = pk_fma2(hz[4], wh2[4], aA);
            aB = pk_fma2(hz[5], wh2[5], aB);
            aA = pk_fma2(hz[6], wh2[6], aA);
            aB = pk_fma2(hz[7], wh2[7], aB);
            f32x2 sS = pk_add2(aA, aB);
            float part = sS.x + sS.y;
            part = dpp_xadd<0xB1>(part);
            part = dpp_xadd<0x4E>(part);
            part = fmaf(axmask, ax_cur, part);   // wave 0 carries the ax term

            float* zb = zbuf + ((sl & 1) << 7);
            zb[zw_idx] = part;                    // publish partial

            __syncthreads();                      // partner partial visible

            // rotate distance-2 AX prefetch (full step before next drain)
            ax_cur = ax_nxt;
            ax_nxt = *axp;
            axp += B_DIM * 16;

            float zv = tanhf_fast(part + zb[zr_idx]);

            unsigned zb32 = __float_as_uint(zv);
            float z[16];
#pragma unroll
            for (int oo = 0; oo < 16; oo++)
                z[oo] = __uint_as_float(__builtin_amdgcn_readlane(zb32, oo * 4));

            // ---- gates for this wave's single feature f ----
            {
                float gp_f = bo[0] + z[0]*wo[0][0] + z[1]*wo[0][1] + z[2]*wo[0][2] + z[3]*wo[0][3];
                float gp_i = bo[1] + z[4]*wo[1][0] + z[5]*wo[1][1] + z[6]*wo[1][2] + z[7]*wo[1][3];
                float gp_g = bo[2] + z[8]*wo[2][0] + z[9]*wo[2][1] + z[10]*wo[2][2] + z[11]*wo[2][3];
                float gp_o = bo[3] + z[12]*wo[3][0] + z[13]*wo[3][1] + z[14]*wo[3][2] + z[15]*wo[3][3];
                float fg = sigf(gp_f);
                float ig = sigf(gp_i);
                float gg = tanhf_fast(gp_g);
                float og = sigf(gp_o);
                c = fg * c + ig * gg;
                float hval = og * tanhf_fast(c);
                *(float*)(hhc + vbase + sl * 512 + woffs[sl]) = hval;
            }

            // read back OWN half slices (in-wave DS ordering; feeds next dot)
            const char* const rp = hhc + vbase + sl * 512 + roffs[sl];
#pragma unroll
            for (int m = 0; m < 4; m++) {
                hz[m * 2]     = *(const f32x2*)(rp + ((m * 64) ^ sw6));
                hz[m * 2 + 1] = *(const f32x2*)(rp + ((m * 64) ^ sw6) + 8);
            }
        }
        vbase += 8 * 512;
    }

    // ================= fused tag head (split mi range across waves) ========
    const int lr = lane & 15;
    const int lg = lane >> 4;
    const bf16x8* wtv = (const bf16x8*)Wtagp;
    bf16x8 wt[4][2];
#pragma unroll
    for (int kk = 0; kk < 4; kk++)
#pragma unroll
        for (int nt = 0; nt < 2; nt++)
            wt[kk][nt] = wtv[(kk * 2 + nt) * 64 + lane];
    float bt0 = btag[lr], bt1 = btag[16 + lr];

    __syncthreads();   // all h history written before head reads

    for (int mi = w * 8; mi < w * 8 + 8; mi++) {
        f32x4 acc0 = (f32x4){0.f, 0.f, 0.f, 0.f};
        f32x4 acc1 = (f32x4){0.f, 0.f, 0.f, 0.f};
        const int arow = mi * 16 + lr;
#pragma unroll
        for (int kk = 0; kk < 4; kk++) {
            float4 lo = *(const float4*)(hhc + hhoff(arow, kk * 128 + lg * 32));
            float4 hi = *(const float4*)(hhc + hhoff(arow, kk * 128 + lg * 32 + 16));
            bf16x8 af;
            af[0] = (short)f2bf(lo.x); af[1] = (short)f2bf(lo.y);
            af[2] = (short)f2bf(lo.z); af[3] = (short)f2bf(lo.w);
            af[4] = (short)f2bf(hi.x); af[5] = (short)f2bf(hi.y);
            af[6] = (short)f2bf(hi.z); af[7] = (short)f2bf(hi.w);
            acc0 = __builtin_amdgcn_mfma_f32_16x16x32_bf16(af, wt[kk][0], acc0, 0, 0, 0);
            acc1 = __builtin_amdgcn_mfma_f32_16x16x32_bf16(af, wt[kk][1], acc1, 0, 0, 0);
        }
        float s0[4], s1[4], mx[4], se[4];
#pragma unroll
        for (int reg = 0; reg < 4; reg++) {
            s0[reg] = acc0[reg] + bt0;
            s1[reg] = acc1[reg] + bt1;
            float m = fmaxf(s0[reg], s1[reg]);
#pragma unroll
            for (int d = 8; d >= 1; d >>= 1) m = fmaxf(m, __shfl_xor(m, d));
            mx[reg] = m;
            float e = __expf(s0[reg] - m) + __expf(s1[reg] - m);
#pragma unroll
            for (int d = 8; d >= 1; d >>= 1) e += __shfl_xor(e, d);
            se[reg] = __logf(e);
        }
#pragma unroll
        for (int reg = 0; reg < 4; reg++) {
            long t = mi * 16 + lg * 4 + reg;
            long base = (t * B_DIM + b) * 32;
            OUT[base + lr]      = s0[reg] - mx[reg] - se[reg];
            OUT[base + 16 + lr] = s1[reg] - mx[reg] - se[reg];
        }
    }
}

// ---------------------------------------------------------------------------
extern "C" void kernel_launch(void* const* d_in, const int* in_sizes, int n_in,
                              void* d_out, int out_size, void* d_ws, size_t ws_size,
                              hipStream_t stream)
{
    const float* X    = (const float*)d_in[0];   // [T,B,F]
    const float* adj  = (const float*)d_in[1];   // [B,B]
    const float* W1   = (const float*)d_in[2];   // [F,H1]
    const float* b1   = (const float*)d_in[3];
    const float* W2   = (const float*)d_in[4];   // [H1,H]
    const float* b2   = (const float*)d_in[5];
    const float* Win  = (const float*)d_in[6];   // [4,F+H,Q]
    const float* b_in = (const float*)d_in[7];   // [4,Q]
    const float* Wout = (const float*)d_in[8];   // [4,Q,H]
    const float* bout = (const float*)d_in[9];   // [4,H]
    const float* Wtag = (const float*)d_in[10];  // [H,TAGS]
    const float* btag = (const float*)d_in[11];
    float* OUT = (float*)d_out;

    float* ws = (float*)d_ws;
    float* NSP  = ws;                    // [T,B,16]  1,048,576 f
    float* adjT = ws + 1048576;          // [B,B]        65,536 f
    float* AX   = ws + 1114112;          // [T,B,16]  1,048,576 f (+over-read slack
                                         //  lands in W1p region, never consumed)
    unsigned short* W1p   = (unsigned short*)(ws + 2162688);   // 32768 bf16
    unsigned short* W2p   = W1p + 32768;                       // 32768 bf16
    unsigned short* Winxp = W2p + 32768;                       //  2048 bf16
    unsigned short* Wtagp = Winxp + 2048;                      //  4096 bf16

    prep_transpose_kernel<<<dim3(128), dim3(256), 0, stream>>>(
        W1, W2, Win, Wtag, adj, W1p, W2p, Winxp, Wtagp, adjT);
    mlp_mfma_kernel<<<dim3(TB / 64), dim3(256), 0, stream>>>(X, W1p, b1, W2p, b2, Winxp, NSP);
    aggx_kernel<<<dim3(256), dim3(256), 0, stream>>>(adjT, NSP, b_in, AX);
    lstm_head_kernel<<<dim3(B_DIM), dim3(128), 0, stream>>>(AX, Win, Wout, bout, Wtagp, btag, OUT);
}

// Round 16
// 136.844 us; speedup vs baseline: 1.0306x; 1.0306x over previous
//
#include <hip/hip_runtime.h>
#include <hip/hip_bf16.h>

// Problem dims (fixed)
#define T_DIM 256
#define B_DIM 256
#define F_DIM 128
#define H1_DIM 256
#define H_DIM 128
#define Q_DIM 4
#define TAGS 32
#define TB (T_DIM * B_DIM)   // 65536 rows

typedef __attribute__((ext_vector_type(8))) short bf16x8;
typedef __attribute__((ext_vector_type(4))) float f32x4;
typedef __attribute__((ext_vector_type(2))) float f32x2;

__device__ __forceinline__ float rcpf(float x) { return __builtin_amdgcn_rcpf(x); }
__device__ __forceinline__ float exp2f_hw(float x) { return __builtin_amdgcn_exp2f(x); }

__device__ __forceinline__ float tanhf_fast(float x) {
    float e = exp2f_hw(2.885390081777927f * x);   // exp(2x)
    return 1.0f - 2.0f * rcpf(e + 1.0f);
}
__device__ __forceinline__ float sigf(float x) {
    return rcpf(1.0f + exp2f_hw(-1.4426950408889634f * x));
}

__device__ __forceinline__ unsigned short f2bf(float f) {
    __hip_bfloat16 h = __float2bfloat16(f);   // RNE
    return *reinterpret_cast<unsigned short*>(&h);
}

// Packed f32 ops (VOP3P): 2 f32 lanes per instruction.
__device__ __forceinline__ f32x2 pk_mul2(f32x2 a, f32x2 b) {
    f32x2 d;
    asm("v_pk_mul_f32 %0, %1, %2" : "=v"(d) : "v"(a), "v"(b));
    return d;
}
__device__ __forceinline__ f32x2 pk_add2(f32x2 a, f32x2 b) {
    f32x2 d;
    asm("v_pk_add_f32 %0, %1, %2" : "=v"(d) : "v"(a), "v"(b));
    return d;
}
__device__ __forceinline__ f32x2 pk_fma2(f32x2 a, f32x2 b, f32x2 c) {
    f32x2 d;
    asm("v_pk_fma_f32 %0, %1, %2, %3" : "=v"(d) : "v"(a), "v"(b), "v"(c));
    return d;
}

// DPP cross-lane add within quad: CTRL=0xB1 -> lane^1, CTRL=0x4E -> lane^2
template<int CTRL>
__device__ __forceinline__ float dpp_xadd(float x) {
    int t = __builtin_amdgcn_update_dpp(0, __float_as_int(x), CTRL, 0xF, 0xF, true);
    return x + __int_as_float(t);
}

// ---------------------------------------------------------------------------
// Kernel 0: weight prep (blocks 0..63) + adj transpose (blocks 64..127).
// ---------------------------------------------------------------------------
__global__ __launch_bounds__(256) void prep_transpose_kernel(
    const float* __restrict__ W1, const float* __restrict__ W2,
    const float* __restrict__ Win, const float* __restrict__ Wtag,
    const float* __restrict__ adj,
    unsigned short* __restrict__ W1p, unsigned short* __restrict__ W2p,
    unsigned short* __restrict__ Winxp, unsigned short* __restrict__ Wtagp,
    float* __restrict__ adjT)
{
    __shared__ float tile[32][33];
    const int tid = threadIdx.x;
    if (blockIdx.x >= 64) {
        const int blk = blockIdx.x - 64;
        const int bx = blk & 7, by = blk >> 3;
        const int lx = tid & 31, ly = (tid >> 5) * 4;
#pragma unroll
        for (int r = 0; r < 4; r++)
            tile[ly + r][lx] = adj[(long)(by * 32 + ly + r) * 256 + bx * 32 + lx];
        __syncthreads();
#pragma unroll
        for (int r = 0; r < 4; r++)
            adjT[(long)(bx * 32 + ly + r) * 256 + by * 32 + lx] = tile[lx][ly + r];
        return;
    }
    const int gid0 = blockIdx.x * 256 + tid;
    const int gstride = 64 * 256;
    for (int idx = gid0; idx < 32768; idx += gstride) {
        int e = idx & 7, l = (idx >> 3) & 63, t2 = idx >> 9;
        int nb = t2 & 15, kk = t2 >> 4;
        int k = kk * 32 + (l >> 4) * 8 + e, n = nb * 16 + (l & 15);
        W1p[idx] = f2bf(W1[k * 256 + n]);
    }
    for (int idx = gid0; idx < 32768; idx += gstride) {
        int e = idx & 7, l = (idx >> 3) & 63, t2 = idx >> 9;
        int nb = t2 & 7, kk = t2 >> 3;
        int k = kk * 32 + (l >> 4) * 8 + e, n = nb * 16 + (l & 15);
        W2p[idx] = f2bf(W2[k * 128 + n]);
    }
    for (int idx = gid0; idx < 2048; idx += gstride) {
        int e = idx & 7, l = (idx >> 3) & 63, kk = idx >> 9;
        int k = kk * 32 + (l >> 4) * 8 + e, o = l & 15;
        Winxp[idx] = f2bf(Win[(o >> 2) * 1024 + k * 4 + (o & 3)]);
    }
    for (int idx = gid0; idx < 4096; idx += gstride) {
        int e = idx & 7, l = (idx >> 3) & 63, t2 = idx >> 9;
        int nt = t2 & 1, kk = t2 >> 1;
        int k = kk * 32 + (l >> 4) * 8 + e, n = nt * 16 + (l & 15);
        Wtagp[idx] = f2bf(Wtag[k * 32 + n]);
    }
}

// ---------------------------------------------------------------------------
// Kernel 1: MFMA MLP + fused Win_x projection.  (unchanged)
// ---------------------------------------------------------------------------
__global__ __launch_bounds__(256) void mlp_mfma_kernel(
    const float* __restrict__ X, const unsigned short* __restrict__ W1p,
    const float* __restrict__ b1, const unsigned short* __restrict__ W2p,
    const float* __restrict__ b2, const unsigned short* __restrict__ Winxp,
    float* __restrict__ NSP)
{
    __shared__ __align__(16) unsigned short a1_s[64 * 256];
    __shared__ __align__(16) unsigned short xns_s[64 * 128];

    const int tid = threadIdx.x;
    const int w = tid >> 6;
    const int lane = tid & 63;
    const int lr = lane & 15;
    const int lg = lane >> 4;
    const long rowbase = (long)blockIdx.x * 64;

    char* const a1c = (char*)a1_s;
    char* const xnc = (char*)xns_s;

    {
        const int r = tid >> 2;
        const int qc = tid & 3;
        const float4* xg = (const float4*)(X + (rowbase + r) * 128 + qc * 32);
#pragma unroll
        for (int i = 0; i < 4; i++) {
            float4 lo = xg[i * 2], hi = xg[i * 2 + 1];
            bf16x8 v;
            v[0] = (short)f2bf(lo.x); v[1] = (short)f2bf(lo.y);
            v[2] = (short)f2bf(lo.z); v[3] = (short)f2bf(lo.w);
            v[4] = (short)f2bf(hi.x); v[5] = (short)f2bf(hi.y);
            v[6] = (short)f2bf(hi.z); v[7] = (short)f2bf(hi.w);
            int byte = (r * 256 + qc * 64 + i * 16) ^ ((r & 7) << 4);
            *(bf16x8*)(xnc + byte) = v;
        }
    }
    __syncthreads();

    {
        f32x4 acc[4][4];
#pragma unroll
        for (int mi = 0; mi < 4; mi++)
#pragma unroll
            for (int j = 0; j < 4; j++) acc[mi][j] = (f32x4){0.f, 0.f, 0.f, 0.f};

        const bf16x8* w1v = (const bf16x8*)W1p;
#pragma unroll
        for (int kk = 0; kk < 4; kk++) {
            bf16x8 af[4];
#pragma unroll
            for (int mi = 0; mi < 4; mi++) {
                int row = mi * 16 + lr;
                int byte = (row * 256 + kk * 64 + lg * 16) ^ ((row & 7) << 4);
                af[mi] = *(const bf16x8*)(xnc + byte);
            }
            bf16x8 bfv[4];
#pragma unroll
            for (int j = 0; j < 4; j++)
                bfv[j] = w1v[(kk * 16 + (w * 4 + j)) * 64 + lane];
#pragma unroll
            for (int mi = 0; mi < 4; mi++)
#pragma unroll
                for (int j = 0; j < 4; j++)
                    acc[mi][j] = __builtin_amdgcn_mfma_f32_16x16x32_bf16(
                        af[mi], bfv[j], acc[mi][j], 0, 0, 0);
        }

        float b1v[4];
#pragma unroll
        for (int j = 0; j < 4; j++) b1v[j] = b1[(w * 4 + j) * 16 + lr];
#pragma unroll
        for (int mi = 0; mi < 4; mi++)
#pragma unroll
            for (int j = 0; j < 4; j++)
#pragma unroll
                for (int reg = 0; reg < 4; reg++) {
                    int row = mi * 16 + lg * 4 + reg;
                    int col = (w * 4 + j) * 16 + lr;
                    float v = tanhf_fast(acc[mi][j][reg] + b1v[j]);
                    int byte = (row * 512 + col * 2) ^ ((row & 7) << 4);
                    *(unsigned short*)(a1c + byte) = f2bf(v);
                }
    }
    __syncthreads();

    {
        f32x4 acc[4][2];
#pragma unroll
        for (int mi = 0; mi < 4; mi++)
#pragma unroll
            for (int j = 0; j < 2; j++) acc[mi][j] = (f32x4){0.f, 0.f, 0.f, 0.f};

        const bf16x8* w2v = (const bf16x8*)W2p;
#pragma unroll
        for (int kk = 0; kk < 8; kk++) {
            bf16x8 af[4];
#pragma unroll
            for (int mi = 0; mi < 4; mi++) {
                int row = mi * 16 + lr;
                int byte = (row * 512 + kk * 64 + lg * 16) ^ ((row & 7) << 4);
                af[mi] = *(const bf16x8*)(a1c + byte);
            }
            bf16x8 bfv[2];
#pragma unroll
            for (int j = 0; j < 2; j++)
                bfv[j] = w2v[(kk * 8 + (w * 2 + j)) * 64 + lane];
#pragma unroll
            for (int mi = 0; mi < 4; mi++)
#pragma unroll
                for (int j = 0; j < 2; j++)
                    acc[mi][j] = __builtin_amdgcn_mfma_f32_16x16x32_bf16(
                        af[mi], bfv[j], acc[mi][j], 0, 0, 0);
        }

        float b2v[2];
#pragma unroll
        for (int j = 0; j < 2; j++) b2v[j] = b2[(w * 2 + j) * 16 + lr];
#pragma unroll
        for (int mi = 0; mi < 4; mi++)
#pragma unroll
            for (int j = 0; j < 2; j++)
#pragma unroll
                for (int reg = 0; reg < 4; reg++) {
                    int row = mi * 16 + lg * 4 + reg;
                    int col = (w * 2 + j) * 16 + lr;
                    float v = tanhf_fast(acc[mi][j][reg] + b2v[j]);
                    int byte = (row * 256 + col * 2) ^ ((row & 7) << 4);
                    *(unsigned short*)(xnc + byte) = f2bf(v);
                }
    }
    __syncthreads();

    {
        f32x4 acc = (f32x4){0.f, 0.f, 0.f, 0.f};
        const bf16x8* wxv = (const bf16x8*)Winxp;
#pragma unroll
        for (int kk = 0; kk < 4; kk++) {
            int row = w * 16 + lr;
            int byte = (row * 256 + kk * 64 + lg * 16) ^ ((row & 7) << 4);
            bf16x8 af = *(const bf16x8*)(xnc + byte);
            bf16x8 bfv = wxv[kk * 64 + lane];
            acc = __builtin_amdgcn_mfma_f32_16x16x32_bf16(af, bfv, acc, 0, 0, 0);
        }
#pragma unroll
        for (int reg = 0; reg < 4; reg++) {
            int row = w * 16 + lg * 4 + reg;
            NSP[(rowbase + row) * 16 + lr] = acc[reg];
        }
    }
}

// ---------------------------------------------------------------------------
// Kernel 3: AX[t,i,o] = b_in[o] + sum_j adj[i,j] * NSP[t,j,o]
// ---------------------------------------------------------------------------
__global__ __launch_bounds__(256) void aggx_kernel(
    const float* __restrict__ adjT, const float* __restrict__ NSP,
    const float* __restrict__ b_in, float* __restrict__ AX)
{
    __shared__ float4 nsp_s[256 * 4];
    const int tid = threadIdx.x;
    const int t = blockIdx.x;
    {
        const float4* g = (const float4*)(NSP + (long)t * 4096);
#pragma unroll
        for (int i = 0; i < 4; i++) nsp_s[tid + i * 256] = g[tid + i * 256];
    }
    __syncthreads();

    float4 acc[4];
#pragma unroll
    for (int p = 0; p < 4; p++) acc[p] = ((const float4*)b_in)[p];

    const float* arow = adjT + tid;
    float a[8], an[8];
#pragma unroll
    for (int m = 0; m < 8; m++) an[m] = arow[m * 256];
    for (int j0 = 0; j0 < 256; j0 += 8) {
#pragma unroll
        for (int m = 0; m < 8; m++) a[m] = an[m];
        if (j0 + 8 < 256) {
#pragma unroll
            for (int m = 0; m < 8; m++) an[m] = arow[(j0 + 8 + m) * 256];
        }
#pragma unroll
        for (int m = 0; m < 8; m++) {
            float av = a[m];
#pragma unroll
            for (int p = 0; p < 4; p++) {
                float4 nv = nsp_s[(j0 + m) * 4 + p];
                acc[p].x += av * nv.x; acc[p].y += av * nv.y;
                acc[p].z += av * nv.z; acc[p].w += av * nv.w;
            }
        }
    }
    float4* out = (float4*)(AX + (long)t * 4096 + tid * 16);
#pragma unroll
    for (int p = 0; p < 4; p++) out[p] = acc[p];
}

// ---------------------------------------------------------------------------
// Kernel 4: LSTM scan + FUSED tag head. TWO waves per batch element.
// Round-16: REVERT to the round-14 structure (best measured: 89.2 us).
// Own-half h reads pre-barrier (in-wave DS ordering), other-half post-barrier,
// weight halves swapped at init for wave 1 so indexing is compile-time.
// (r15's partial-z exchange serialized TWO LDS hops in the chain - regressed.)
// ---------------------------------------------------------------------------
__device__ __forceinline__ int hhoff(int row, int inrow) {
    return (row * 512 + inrow) ^ ((row & 7) << 4);
}

__global__ __attribute__((amdgpu_waves_per_eu(1, 1))) __launch_bounds__(128)
void lstm_head_kernel(
    const float* __restrict__ AX, const float* __restrict__ Win,
    const float* __restrict__ Wout, const float* __restrict__ b_out,
    const unsigned short* __restrict__ Wtagp, const float* __restrict__ btag,
    float* __restrict__ OUT)
{
    __shared__ __align__(16) float hh[T_DIM * 128];   // 128 KB, swizzled rows
    char* const hhc = (char*)hh;

    const int tid = threadIdx.x;
    const int w = tid >> 6;        // wave: h-half owner (features w*64..w*64+63)
    const int lane = tid & 63;
    const int b = blockIdx.x;
    const int o = lane >> 2;
    const int s = lane & 3;
    const int g_o = o >> 2, q_o = o & 3;

    // wh2: [0..7] = k in [0,64) (pairs), [8..15] = k in [64,128)
    f32x2 wh2[16];
#pragma unroll
    for (int m = 0; m < 8; m++)
#pragma unroll
        for (int p = 0; p < 2; p++) {
            int k0 = m * 16 + s * 4 + p * 2;
            f32x2 v;
            v.x = Win[g_o * 1024 + 512 + k0 * 4 + q_o];
            v.y = Win[g_o * 1024 + 512 + (k0 + 1) * 4 + q_o];
            wh2[m * 2 + p] = v;
        }
    // swap halves for wave 1 so wh2[0..7] always multiplies the OWN half
    {
        const bool sw = (w == 1);
#pragma unroll
        for (int i = 0; i < 8; i++) {
            f32x2 a = wh2[i], bv = wh2[i + 8];
            wh2[i]     = sw ? bv : a;
            wh2[i + 8] = sw ? a : bv;
        }
    }

    // gate weights for THIS wave's feature f = w*64 + lane
    const int f = w * 64 + lane;
    float wo[4][4];
    float bo[4];
#pragma unroll
    for (int g = 0; g < 4; g++) {
        bo[g] = b_out[g * 128 + f];
#pragma unroll
        for (int q = 0; q < 4; q++)
            wo[g][q] = Wout[(g * 4 + q) * 128 + f];
    }

    const int own_off = w << 8;          // byte base of own half within a row
    const int oth_off = own_off ^ 256;   // other half
    int woffs[8], roffs[8];
#pragma unroll
    for (int sl = 0; sl < 8; sl++) {
        woffs[sl] = ((lane * 4) ^ (sl << 4)) + own_off;
        roffs[sl] = (s * 16) ^ ((sl << 4) & 0x30);
    }

    float c = 0.f;
    f32x2 hown[8], hoth[8];
#pragma unroll
    for (int m = 0; m < 8; m++) { hown[m] = (f32x2){0.f, 0.f}; hoth[m] = (f32x2){0.f, 0.f}; }

    const float* axp = AX + (long)b * 16 + o;
    float ax_cur = axp[0];
    float ax_nxt = axp[B_DIM * 16];
    axp += 2 * B_DIM * 16;

    int vbase = 0;
    for (int tb = 0; tb < T_DIM; tb += 8) {
#pragma unroll
        for (int sl = 0; sl < 8; sl++) {
            const int sw6 = (sl << 4) & 0x40;
            // ---- packed dot: own half first (regs ready), other half second ----
            f32x2 aA = pk_mul2(hown[0], wh2[0]);
            f32x2 aB = pk_mul2(hown[1], wh2[1]);
            f32x2 aC = pk_mul2(hown[2], wh2[2]);
            f32x2 aD = pk_mul2(hown[3], wh2[3]);
            aA = pk_fma2(hown[4], wh2[4], aA);
            aB = pk_fma2(hown[5], wh2[5], aB);
            aC = pk_fma2(hown[6], wh2[6], aC);
            aD = pk_fma2(hown[7], wh2[7], aD);
            aA = pk_fma2(hoth[0], wh2[8],  aA);
            aB = pk_fma2(hoth[1], wh2[9],  aB);
            aC = pk_fma2(hoth[2], wh2[10], aC);
            aD = pk_fma2(hoth[3], wh2[11], aD);
            aA = pk_fma2(hoth[4], wh2[12], aA);
            aB = pk_fma2(hoth[5], wh2[13], aB);
            aC = pk_fma2(hoth[6], wh2[14], aC);
            aD = pk_fma2(hoth[7], wh2[15], aD);
            f32x2 sAB = pk_add2(aA, aB);
            f32x2 sCD = pk_add2(aC, aD);
            f32x2 sS  = pk_add2(sAB, sCD);
            float acc = sS.x + sS.y;
            acc = dpp_xadd<0xB1>(acc);
            acc = dpp_xadd<0x4E>(acc);
            float zv = tanhf_fast(acc + ax_cur);

            unsigned zb = __float_as_uint(zv);
            float z[16];
#pragma unroll
            for (int oo = 0; oo < 16; oo++)
                z[oo] = __uint_as_float(__builtin_amdgcn_readlane(zb, oo * 4));

            // ---- gates for this wave's single feature f ----
            {
                float gp_f = bo[0] + z[0]*wo[0][0] + z[1]*wo[0][1] + z[2]*wo[0][2] + z[3]*wo[0][3];
                float gp_i = bo[1] + z[4]*wo[1][0] + z[5]*wo[1][1] + z[6]*wo[1][2] + z[7]*wo[1][3];
                float gp_g = bo[2] + z[8]*wo[2][0] + z[9]*wo[2][1] + z[10]*wo[2][2] + z[11]*wo[2][3];
                float gp_o = bo[3] + z[12]*wo[3][0] + z[13]*wo[3][1] + z[14]*wo[3][2] + z[15]*wo[3][3];
                float fg = sigf(gp_f);
                float ig = sigf(gp_i);
                float gg = tanhf_fast(gp_g);
                float og = sigf(gp_o);
                c = fg * c + ig * gg;
                float hval = og * tanhf_fast(c);
                *(float*)(hhc + vbase + sl * 512 + woffs[sl]) = hval;
            }

            // pre-barrier: read back OWN half (in-wave DS ordering makes this
            // correct; latency hides under the barrier's lgkm drain)
            const char* const rp = hhc + vbase + sl * 512 + roffs[sl];
#pragma unroll
            for (int m = 0; m < 4; m++) {
                float4 v4 = *(const float4*)(rp + own_off + ((m * 64) ^ sw6));
                hown[m * 2]     = (f32x2){v4.x, v4.y};
                hown[m * 2 + 1] = (f32x2){v4.z, v4.w};
            }

            __syncthreads();   // other wave's half now visible

            // rotate distance-2 AX prefetch right after the barrier
            ax_cur = ax_nxt;
            ax_nxt = *axp;
            axp += B_DIM * 16;

            // post-barrier: read the OTHER wave's half
#pragma unroll
            for (int m = 0; m < 4; m++) {
                float4 v4 = *(const float4*)(rp + oth_off + ((m * 64) ^ sw6));
                hoth[m * 2]     = (f32x2){v4.x, v4.y};
                hoth[m * 2 + 1] = (f32x2){v4.z, v4.w};
            }
        }
        vbase += 8 * 512;
    }

    // ================= fused tag head (split mi range across waves) ========
    const int lr = lane & 15;
    const int lg = lane >> 4;
    const bf16x8* wtv = (const bf16x8*)Wtagp;
    bf16x8 wt[4][2];
#pragma unroll
    for (int kk = 0; kk < 4; kk++)
#pragma unroll
        for (int nt = 0; nt < 2; nt++)
            wt[kk][nt] = wtv[(kk * 2 + nt) * 64 + lane];
    float bt0 = btag[lr], bt1 = btag[16 + lr];

    for (int mi = w * 8; mi < w * 8 + 8; mi++) {
        f32x4 acc0 = (f32x4){0.f, 0.f, 0.f, 0.f};
        f32x4 acc1 = (f32x4){0.f, 0.f, 0.f, 0.f};
        const int arow = mi * 16 + lr;
#pragma unroll
        for (int kk = 0; kk < 4; kk++) {
            float4 lo = *(const float4*)(hhc + hhoff(arow, kk * 128 + lg * 32));
            float4 hi = *(const float4*)(hhc + hhoff(arow, kk * 128 + lg * 32 + 16));
            bf16x8 af;
            af[0] = (short)f2bf(lo.x); af[1] = (short)f2bf(lo.y);
            af[2] = (short)f2bf(lo.z); af[3] = (short)f2bf(lo.w);
            af[4] = (short)f2bf(hi.x); af[5] = (short)f2bf(hi.y);
            af[6] = (short)f2bf(hi.z); af[7] = (short)f2bf(hi.w);
            acc0 = __builtin_amdgcn_mfma_f32_16x16x32_bf16(af, wt[kk][0], acc0, 0, 0, 0);
            acc1 = __builtin_amdgcn_mfma_f32_16x16x32_bf16(af, wt[kk][1], acc1, 0, 0, 0);
        }
        float s0[4], s1[4], mx[4], se[4];
#pragma unroll
        for (int reg = 0; reg < 4; reg++) {
            s0[reg] = acc0[reg] + bt0;
            s1[reg] = acc1[reg] + bt1;
            float m = fmaxf(s0[reg], s1[reg]);
#pragma unroll
            for (int d = 8; d >= 1; d >>= 1) m = fmaxf(m, __shfl_xor(m, d));
            mx[reg] = m;
            float e = __expf(s0[reg] - m) + __expf(s1[reg] - m);
#pragma unroll
            for (int d = 8; d >= 1; d >>= 1) e += __shfl_xor(e, d);
            se[reg] = __logf(e);
        }
#pragma unroll
        for (int reg = 0; reg < 4; reg++) {
            long t = mi * 16 + lg * 4 + reg;
            long base = (t * B_DIM + b) * 32;
            OUT[base + lr]      = s0[reg] - mx[reg] - se[reg];
            OUT[base + 16 + lr] = s1[reg] - mx[reg] - se[reg];
        }
    }
}

// ---------------------------------------------------------------------------
extern "C" void kernel_launch(void* const* d_in, const int* in_sizes, int n_in,
                              void* d_out, int out_size, void* d_ws, size_t ws_size,
                              hipStream_t stream)
{
    const float* X    = (const float*)d_in[0];   // [T,B,F]
    const float* adj  = (const float*)d_in[1];   // [B,B]
    const float* W1   = (const float*)d_in[2];   // [F,H1]
    const float* b1   = (const float*)d_in[3];
    const float* W2   = (const float*)d_in[4];   // [H1,H]
    const float* b2   = (const float*)d_in[5];
    const float* Win  = (const float*)d_in[6];   // [4,F+H,Q]
    const float* b_in = (const float*)d_in[7];   // [4,Q]
    const float* Wout = (const float*)d_in[8];   // [4,Q,H]
    const float* bout = (const float*)d_in[9];   // [4,H]
    const float* Wtag = (const float*)d_in[10];  // [H,TAGS]
    const float* btag = (const float*)d_in[11];
    float* OUT = (float*)d_out;

    float* ws = (float*)d_ws;
    float* NSP  = ws;                    // [T,B,16]  1,048,576 f
    float* adjT = ws + 1048576;          // [B,B]        65,536 f
    float* AX   = ws + 1114112;          // [T,B,16]  1,048,576 f (+over-read slack
                                         //  lands in W1p region, never consumed)
    unsigned short* W1p   = (unsigned short*)(ws + 2162688);   // 32768 bf16
    unsigned short* W2p   = W1p + 32768;                       // 32768 bf16
    unsigned short* Winxp = W2p + 32768;                       //  2048 bf16
    unsigned short* Wtagp = Winxp + 2048;                      //  4096 bf16

    prep_transpose_kernel<<<dim3(128), dim3(256), 0, stream>>>(
        W1, W2, Win, Wtag, adj, W1p, W2p, Winxp, Wtagp, adjT);
    mlp_mfma_kernel<<<dim3(TB / 64), dim3(256), 0, stream>>>(X, W1p, b1, W2p, b2, Winxp, NSP);
    aggx_kernel<<<dim3(256), dim3(256), 0, stream>>>(adjT, NSP, b_in, AX);
    lstm_head_kernel<<<dim3(B_DIM), dim3(128), 0, stream>>>(AX, Win, Wout, bout, Wtagp, btag, OUT);
}